// Round 1
// baseline (596.715 us; speedup 1.0000x reference)
//
#include <hip/hip_runtime.h>

// PulseFloatingPointEncoder: per element emit 8 fp32 flags
// [sign, e3, e2, e1, e0, m2, m1, m0] of a truncated e4m3-style encoding.
// E_BITS=4, M_BITS=3, N_INT=10, N_DEC=10, BIAS=7, START_EXP=17, SUB_START=16.

__device__ __forceinline__ void encode_one(float x, float4& lo, float4& hi) {
    float sign = (x < 0.0f) ? 1.0f : 0.0f;   // note: -0.0f -> 0 (matches ref x<0)
    unsigned ub = __float_as_uint(x) & 0x7fffffffu;
    float a = __uint_as_float(ub);
    int e_lead = (int)(ub >> 23) - 127;      // floor(log2 a) for normals; <=-127 for subnorm/zero

    int ec, mant;
    if (__builtin_expect(e_lead >= 10, 0)) {
        // a >= 1024 (or inf/nan): faithful emulation of the reference greedy scan.
        float V = a;
        int has_fired = 0, d0 = 0, d1 = 0, d2 = 0;
        int e_reg = 0, m0 = 0, m1 = 0, m2 = 0;
        for (int t = 0; t < 20; ++t) {
            float thr = __builtin_exp2f((float)(9 - t));   // exact powers of two
            int s = (V >= thr) ? 1 : 0;
            if (s) V -= thr;                                // exact: V - s*thr
            int fs = s & (has_fired ^ 1);
            int active = (t < 16) ? 1 : 0;
            int counter = (16 - t) > 0 ? (16 - t) : 0;
            if (fs & active) e_reg |= (counter & 15);
            if (s) { m0 |= d0; m1 |= d1; m2 |= d2; }
            int vfs = fs & active;
            d2 = d1; d1 = d0; d0 = vfs;
            has_fired |= vfs;
            if (t >= 16 && t <= 18) {
                int bit = s & (has_fired ^ 1);
                if (t == 16) m0 |= bit; else if (t == 17) m1 |= bit; else m2 |= bit;
            }
        }
        ec = e_reg;
        mant = (m0 << 2) | (m1 << 1) | m2;
    } else {
        bool norm = (e_lead >= -6);
        bool sub  = (e_lead >= -10) & !norm;
        // normal: exponent code (7+e_lead)&15, mantissa = top 3 fraction bits (truncate)
        int ec_n   = (7 + e_lead) & 15;
        int mant_n = (int)(ub >> 20) & 7;
        // subnormal range [2^-10, 2^-6): bits at weights 2^-7..2^-9
        int mant_s = ((int)(a * 512.0f)) & 7;   // a*512 in [0.5, 8), exact scaling, trunc
        ec   = norm ? ec_n : 0;
        mant = norm ? mant_n : (sub ? mant_s : 0);
    }

    lo.x = sign;
    lo.y = (float)((ec >> 3) & 1);   // e_out is e_reg reversed => MSB first
    lo.z = (float)((ec >> 2) & 1);
    lo.w = (float)((ec >> 1) & 1);
    hi.x = (float)(ec & 1);
    hi.y = (float)((mant >> 2) & 1); // m_reg[0] = most significant mantissa bit
    hi.z = (float)((mant >> 1) & 1);
    hi.w = (float)(mant & 1);
}

__global__ __launch_bounds__(256) void pulse_encode_kernel(
        const float* __restrict__ in, float4* __restrict__ out, int n) {
    int i = blockIdx.x * 256 + threadIdx.x;
    if (i >= n) return;
    float4 lo, hi;
    encode_one(in[i], lo, hi);
    out[2 * i]     = lo;
    out[2 * i + 1] = hi;
}

extern "C" void kernel_launch(void* const* d_in, const int* in_sizes, int n_in,
                              void* d_out, int out_size, void* d_ws, size_t ws_size,
                              hipStream_t stream) {
    const float* x = (const float*)d_in[0];
    float4* out = (float4*)d_out;
    int n = in_sizes[0];                  // 8*2048*1024 = 16,777,216
    int blocks = (n + 255) / 256;
    pulse_encode_kernel<<<blocks, 256, 0, stream>>>(x, out, n);
}